// Round 4
// baseline (786.649 us; speedup 1.0000x reference)
//
#include <hip/hip_runtime.h>
#include <type_traits>

typedef __bf16 bf16x8 __attribute__((ext_vector_type(8)));
typedef __bf16 bf16x4 __attribute__((ext_vector_type(4)));
typedef float floatx4 __attribute__((ext_vector_type(4)));

__device__ __forceinline__ void gl_lds16(const __bf16* g, const __bf16* l) {
  __builtin_amdgcn_global_load_lds(
      (const __attribute__((address_space(1))) unsigned int*)g,
      (__attribute__((address_space(3))) unsigned int*)l, 16, 0, 0);
}

// =====================================================================
// GEMM: C[M,N] = A[M,K] bf16 (lda) x Bt[N,K]^T bf16 (ldb) [+bias]*cscale
// blockIdx.z = zb*nsplit + zs; A/B advance zb*sA/sB + zs*K; C slice z*sC.
// =====================================================================
template <int BM, int BN>
__global__ __launch_bounds__(256)
void gemm_nt(const __bf16* __restrict__ A, const __bf16* __restrict__ Bt,
             const float* __restrict__ bias, void* __restrict__ Cv,
             int K, int lda, int ldb, int ldc, int bf16_out, float cscale,
             long sA, long sB, long sC, int nsplit)
{
  constexpr int MI = BM / 32;
  constexpr int NJ = BN / 32;
  __shared__ __align__(16) __bf16 As[BM * 32];
  __shared__ __align__(16) __bf16 Bs[BN * 32];
  const int tid = threadIdx.x;
  const int bm = blockIdx.y * BM, bn = blockIdx.x * BN;
  const int zb = blockIdx.z / nsplit, zs = blockIdx.z % nsplit;
  const __bf16* Ab = A  + (size_t)zb * sA + (size_t)zs * K;
  const __bf16* Bb = Bt + (size_t)zb * sB + (size_t)zs * K;
  const int wave = tid >> 6, lane = tid & 63;
  const int wm = (wave & 1) * (BM / 2), wn = (wave >> 1) * (BN / 2);
  const int lrow = lane & 15, quad = lane >> 4;
  const int srow = tid >> 2, scol = (tid & 3) << 3;

  const __bf16* Ap = Ab + (size_t)(bm + srow) * lda + scol;
  const __bf16* Bp = Bb + (size_t)(bn + srow) * ldb + scol;

  floatx4 acc[MI][NJ];
#pragma unroll
  for (int i = 0; i < MI; ++i)
#pragma unroll
    for (int j = 0; j < NJ; ++j) acc[i][j] = floatx4{0.f, 0.f, 0.f, 0.f};

  for (int k0 = 0; k0 < K; k0 += 32) {
#pragma unroll
    for (int r = 0; r < BM / 64; ++r)
      gl_lds16(Ap + (size_t)(64 * r) * lda + k0, &As[tid * 8 + r * 2048]);
#pragma unroll
    for (int r = 0; r < BN / 64; ++r)
      gl_lds16(Bp + (size_t)(64 * r) * ldb + k0, &Bs[tid * 8 + r * 2048]);
    __syncthreads();
    bf16x8 af[MI], bfr[NJ];
#pragma unroll
    for (int i = 0; i < MI; ++i)
      af[i] = *(const bf16x8*)&As[(wm + i * 16 + lrow) * 32 + (quad << 3)];
#pragma unroll
    for (int j = 0; j < NJ; ++j)
      bfr[j] = *(const bf16x8*)&Bs[(wn + j * 16 + lrow) * 32 + (quad << 3)];
#pragma unroll
    for (int i = 0; i < MI; ++i)
#pragma unroll
      for (int j = 0; j < NJ; ++j)
        acc[i][j] = __builtin_amdgcn_mfma_f32_16x16x32_bf16(af[i], bfr[j], acc[i][j], 0, 0, 0);
    __syncthreads();
  }

  // C/D layout (verified m89/m91): col = lane&15, row = quad*4 + reg
  if (bf16_out) {
    __bf16* C = (__bf16*)Cv + (size_t)blockIdx.z * sC;
#pragma unroll
    for (int i = 0; i < MI; ++i) {
      const int row0 = bm + wm + i * 16 + (quad << 2);
#pragma unroll
      for (int j = 0; j < NJ; ++j) {
        const int col = bn + wn + j * 16 + lrow;
        const float bv = bias ? bias[col] : 0.f;
#pragma unroll
        for (int r = 0; r < 4; ++r)
          C[(size_t)(row0 + r) * ldc + col] = (__bf16)((acc[i][j][r] + bv) * cscale);
      }
    }
  } else {
    float* C = (float*)Cv + (size_t)blockIdx.z * sC;
#pragma unroll
    for (int i = 0; i < MI; ++i) {
      const int row0 = bm + wm + i * 16 + (quad << 2);
#pragma unroll
      for (int j = 0; j < NJ; ++j) {
        const int col = bn + wn + j * 16 + lrow;
        const float bv = bias ? bias[col] : 0.f;
#pragma unroll
        for (int r = 0; r < 4; ++r)
          C[(size_t)(row0 + r) * ldc + col] = (acc[i][j][r] + bv) * cscale;
      }
    }
  }
}

// ---- generic split-K reduce (x8): out[z*obs + r*ldo + c] ----
__global__ __launch_bounds__(256)
void reduce_kernel(const __bf16* __restrict__ part, __bf16* __restrict__ out,
                   const float* __restrict__ bias, int N, int ldo, long obs,
                   long sC, int nsplit, float scale)
{
  const long idx = ((long)blockIdx.x * 256 + threadIdx.x) * 8;
  const int r = (int)(idx / N), c = (int)(idx % N);
  const __bf16* p0 = part + (size_t)blockIdx.z * nsplit * sC + idx;
  float a[8] = {0, 0, 0, 0, 0, 0, 0, 0};
  for (int s = 0; s < nsplit; ++s) {
    bf16x8 v = *(const bf16x8*)(p0 + (size_t)s * sC);
#pragma unroll
    for (int i = 0; i < 8; ++i) a[i] += (float)v[i];
  }
  if (bias) {
#pragma unroll
    for (int i = 0; i < 8; ++i) a[i] += bias[c + i];
  }
  bf16x8 o;
#pragma unroll
  for (int i = 0; i < 8; ++i) o[i] = (__bf16)(a[i] * scale);
  *(bf16x8*)(out + (size_t)blockIdx.z * obs + (size_t)r * ldo + c) = o;
}

// ---- fused: sum nsplit slices + bias -> LayerNorm(sc,bi) -> ReLU -> bf16 (cols=2048) ----
__global__ __launch_bounds__(256)
void reduce_ln_relu(const __bf16* __restrict__ P, long sC, int nsplit,
                    const float* __restrict__ bias, const float* __restrict__ sc,
                    const float* __restrict__ bi, __bf16* __restrict__ out)
{
  const int row = blockIdx.x;
  const int c = threadIdx.x << 3;
  const __bf16* p0 = P + (size_t)row * 2048 + c;
  float f[8] = {0, 0, 0, 0, 0, 0, 0, 0};
  for (int s = 0; s < nsplit; ++s) {
    bf16x8 v = *(const bf16x8*)(p0 + (size_t)s * sC);
#pragma unroll
    for (int i = 0; i < 8; ++i) f[i] += (float)v[i];
  }
  float su = 0.f, ss = 0.f;
#pragma unroll
  for (int i = 0; i < 8; ++i) { f[i] += bias[c + i]; su += f[i]; ss += f[i] * f[i]; }
  __shared__ float shs[4], shss[4];
  const int lane = threadIdx.x & 63, w = threadIdx.x >> 6;
  for (int o = 32; o; o >>= 1) { su += __shfl_down(su, o, 64); ss += __shfl_down(ss, o, 64); }
  if (!lane) { shs[w] = su; shss[w] = ss; }
  __syncthreads();
  const float fs = shs[0] + shs[1] + shs[2] + shs[3];
  const float fss = shss[0] + shss[1] + shss[2] + shss[3];
  const float mu = fs * (1.f / 2048.f);
  const float rstd = rsqrtf(fss * (1.f / 2048.f) - mu * mu + 1e-6f);
  bf16x8 o;
#pragma unroll
  for (int i = 0; i < 8; ++i)
    o[i] = (__bf16)fmaxf((f[i] - mu) * rstd * sc[c + i] + bi[c + i], 0.f);
  *(bf16x8*)&out[(size_t)row * 2048 + c] = o;
}

// ---- fused: p_t = p_prev + (sum slices + bp2); fp32 + bf16 out (2048x1024) ----
__global__ __launch_bounds__(256)
void reduce_p_combine(const __bf16* __restrict__ P, long sC, int nsplit,
                      const float* __restrict__ bp2, const float* __restrict__ p_prev,
                      float* __restrict__ p_out, __bf16* __restrict__ p_bf)
{
  const long idx = ((long)blockIdx.x * 256 + threadIdx.x) * 8;
  const int c = (int)(idx & 1023);
  float a[8] = {0, 0, 0, 0, 0, 0, 0, 0};
  for (int s = 0; s < nsplit; ++s) {
    bf16x8 v = *(const bf16x8*)(P + (size_t)s * sC + idx);
#pragma unroll
    for (int i = 0; i < 8; ++i) a[i] += (float)v[i];
  }
  bf16x8 ob;
#pragma unroll
  for (int i = 0; i < 8; ++i) {
    const float p = p_prev[idx + i] + a[i] + bp2[c + i];
    p_out[idx + i] = p;
    ob[i] = (__bf16)p;
  }
  *(bf16x8*)&p_bf[idx] = ob;
}

// ---- fused: g = sigmoid(sum slices + bg); s = clip(s_prev + g*pu + (1-g)*wu) ----
__global__ __launch_bounds__(256)
void s_final_fused(const __bf16* __restrict__ P, long sC, int nsplit,
                   const float* __restrict__ bg, const float* __restrict__ s_prev,
                   const float* __restrict__ pu, const float* __restrict__ wu,
                   float* __restrict__ s_out)
{
  const long idx = ((long)blockIdx.x * 256 + threadIdx.x) * 8;
  const int c = (int)(idx & 1023);
  float a[8] = {0, 0, 0, 0, 0, 0, 0, 0};
  for (int s = 0; s < nsplit; ++s) {
    bf16x8 v = *(const bf16x8*)(P + (size_t)s * sC + idx);
#pragma unroll
    for (int i = 0; i < 8; ++i) a[i] += (float)v[i];
  }
#pragma unroll
  for (int i = 0; i < 8; ++i) {
    const float g = 1.f / (1.f + expf(-(a[i] + bg[c + i])));
    float s = s_prev[idx + i] + g * pu[idx + i] + (1.f - g) * wu[idx + i];
    s_out[idx + i] = fminf(fmaxf(s, -10.f), 10.f);
  }
}

// ---- batched fp32 [R,C] -> bf16 [C,R] transpose-convert ----
struct TSegs {
  const float* src[16]; __bf16* dst[16];
  int R[16], C[16]; int prefix[17]; int nseg;
};
__global__ __launch_bounds__(256)
void tconv_batch(TSegs t)
{
  __shared__ float tile[32][33];
  int s = 0;
  while (s < t.nseg - 1 && (int)blockIdx.x >= t.prefix[s + 1]) ++s;
  const int local = blockIdx.x - t.prefix[s];
  const int Ct = t.C[s] >> 5;
  const int tr = local / Ct, tc = local - tr * Ct;
  const int r0 = tr << 5, c0 = tc << 5;
  const float* src = t.src[s];
  __bf16* dst = t.dst[s];
  const int R = t.R[s], C = t.C[s];
  const int x = threadIdx.x & 31, y = threadIdx.x >> 5;
#pragma unroll
  for (int i = 0; i < 32; i += 8)
    tile[y + i][x] = src[(size_t)(r0 + y + i) * C + c0 + x];
  __syncthreads();
#pragma unroll
  for (int i = 0; i < 32; i += 8)
    dst[(size_t)(c0 + y + i) * R + r0 + x] = (__bf16)tile[x][y + i];
}

// ---- batched fp32 -> bf16 (strided rows) ----
struct FSegs {
  const float* src[16]; __bf16* dst[16];
  int rows[16], cols[16], sld[16], dld[16]; int prefix[17]; int nseg;
};
__global__ __launch_bounds__(256)
void f2b_batch(FSegs t)
{
  int s = 0;
  while (s < t.nseg - 1 && (int)blockIdx.x >= t.prefix[s + 1]) ++s;
  const long e = ((long)(blockIdx.x - t.prefix[s]) * 256 + threadIdx.x) * 4;
  const int cols = t.cols[s];
  if (e >= (long)t.rows[s] * cols) return;
  const int r = (int)(e / cols), c = (int)(e % cols);
  float4 v = *(const float4*)(t.src[s] + (size_t)r * t.sld[s] + c);
  bf16x4 o;
  o[0] = (__bf16)v.x; o[1] = (__bf16)v.y; o[2] = (__bf16)v.z; o[3] = (__bf16)v.w;
  *(bf16x4*)(t.dst[s] + (size_t)r * t.dld[s] + c) = o;
}

// ---- in-place row softmax on bf16, cols=4096 ----
__global__ __launch_bounds__(256)
void softmax_bf16_kernel(__bf16* __restrict__ x)
{
  __bf16* xr = x + (size_t)blockIdx.x * 4096;
  bf16x8 v0 = *(const bf16x8*)&xr[threadIdx.x * 16];
  bf16x8 v1 = *(const bf16x8*)&xr[threadIdx.x * 16 + 8];
  float f[16];
#pragma unroll
  for (int i = 0; i < 8; ++i) { f[i] = (float)v0[i]; f[i + 8] = (float)v1[i]; }
  float m = f[0];
#pragma unroll
  for (int i = 1; i < 16; ++i) m = fmaxf(m, f[i]);
  __shared__ float sh[4];
  const int lane = threadIdx.x & 63, w = threadIdx.x >> 6;
  for (int o = 32; o; o >>= 1) m = fmaxf(m, __shfl_down(m, o, 64));
  if (!lane) sh[w] = m;
  __syncthreads();
  m = fmaxf(fmaxf(sh[0], sh[1]), fmaxf(sh[2], sh[3]));
  __syncthreads();
  float s = 0.f;
#pragma unroll
  for (int i = 0; i < 16; ++i) { f[i] = expf(f[i] - m); s += f[i]; }
  for (int o = 32; o; o >>= 1) s += __shfl_down(s, o, 64);
  if (!lane) sh[w] = s;
  __syncthreads();
  const float rs = 1.f / (sh[0] + sh[1] + sh[2] + sh[3]);
  bf16x8 o0, o1;
#pragma unroll
  for (int i = 0; i < 8; ++i) { o0[i] = (__bf16)(f[i] * rs); o1[i] = (__bf16)(f[i + 8] * rs); }
  *(bf16x8*)&xr[threadIdx.x * 16] = o0;
  *(bf16x8*)&xr[threadIdx.x * 16 + 8] = o1;
}

// ---- mix = softmax(ctx_cat @ Wmix + bmix) ----
__global__ __launch_bounds__(256)
void wmix_kernel(const __bf16* __restrict__ ctx, const float* __restrict__ Wm,
                 const float* __restrict__ bm, float* __restrict__ mix)
{
  const int row = blockIdx.x;
  const __bf16* cr = ctx + (size_t)row * 3072;
  float a0 = 0.f, a1 = 0.f, a2 = 0.f;
  for (int c = threadIdx.x; c < 3072; c += 256) {
    float v = (float)cr[c];
    a0 = fmaf(v, Wm[c * 3 + 0], a0);
    a1 = fmaf(v, Wm[c * 3 + 1], a1);
    a2 = fmaf(v, Wm[c * 3 + 2], a2);
  }
  __shared__ float sh[3][4];
  const int lane = threadIdx.x & 63, w = threadIdx.x >> 6;
  for (int o = 32; o; o >>= 1) {
    a0 += __shfl_down(a0, o, 64); a1 += __shfl_down(a1, o, 64); a2 += __shfl_down(a2, o, 64);
  }
  if (!lane) { sh[0][w] = a0; sh[1][w] = a1; sh[2][w] = a2; }
  __syncthreads();
  if (threadIdx.x == 0) {
    float l0 = sh[0][0] + sh[0][1] + sh[0][2] + sh[0][3] + bm[0];
    float l1 = sh[1][0] + sh[1][1] + sh[1][2] + sh[1][3] + bm[1];
    float l2 = sh[2][0] + sh[2][1] + sh[2][2] + sh[2][3] + bm[2];
    float mm = fmaxf(l0, fmaxf(l1, l2));
    float e0 = expf(l0 - mm), e1 = expf(l1 - mm), e2 = expf(l2 - mm);
    float rs = 1.f / (e0 + e1 + e2);
    mix[row * 4 + 0] = e0 * rs; mix[row * 4 + 1] = e1 * rs; mix[row * 4 + 2] = e2 * rs;
  }
}

// ---- c_t -> 3 concat buffers ----
__global__ __launch_bounds__(256)
void ct_combine_kernel(const __bf16* __restrict__ ctx, const float* __restrict__ mix,
                       __bf16* __restrict__ cz, __bf16* __restrict__ pc,
                       __bf16* __restrict__ sec)
{
  const int idx = blockIdx.x * 256 + threadIdx.x;
  const int row = idx >> 10, d = idx & 1023;
  const __bf16* cr = ctx + (size_t)row * 3072 + d;
  const float v = mix[row * 4 + 0] * (float)cr[0] +
                  mix[row * 4 + 1] * (float)cr[1024] +
                  mix[row * 4 + 2] * (float)cr[2048];
  const __bf16 b = (__bf16)v;
  cz[(size_t)row * 2048 + d] = b;
  pc[(size_t)row * 2048 + 1024 + d] = b;
  sec[(size_t)row * 3072 + 2048 + d] = b;
}

// ---- w_t: bf16 uv/amod/wB inputs ----
__global__ __launch_bounds__(256)
void w_combine_kernel(const float* __restrict__ w_prev, const __bf16* __restrict__ uv,
                      const __bf16* __restrict__ amod, const __bf16* __restrict__ wB,
                      const float* __restrict__ A_diag, float* __restrict__ w_out,
                      __bf16* __restrict__ w_bf)
{
  const int idx = blockIdx.x * 256 + threadIdx.x;
  const int d = idx & 511;
  const float Ad = tanhf(A_diag[d]) * 0.9f;
  const float wl = fmaf(Ad, w_prev[idx], (float)uv[idx]);
  const float w = fmaf(tanhf((float)amod[idx]), wl, (float)wB[idx]);
  w_out[idx] = w;
  w_bf[idx] = (__bf16)w;
}

// =====================================================================
extern "C" void kernel_launch(void* const* d_in, const int* in_sizes, int n_in,
                              void* d_out, int out_size, void* d_ws, size_t ws_size,
                              hipStream_t stream)
{
  const float* s_prev = (const float*)d_in[0];
  const float* w_prev = (const float*)d_in[1];
  const float* p_prev = (const float*)d_in[2];
  const float* e_t    = (const float*)d_in[3];
  const float* M0 = (const float*)d_in[4];
  const float* M1 = (const float*)d_in[5];
  const float* M2 = (const float*)d_in[6];
  const float* K0 = (const float*)d_in[7];
  const float* K1 = (const float*)d_in[8];
  const float* K2 = (const float*)d_in[9];
  const float* Wq1 = (const float*)d_in[10];
  const float* bq1 = (const float*)d_in[11];
  const float* lnq_s = (const float*)d_in[12];
  const float* lnq_b = (const float*)d_in[13];
  const float* Wq2 = (const float*)d_in[14];
  const float* bq2 = (const float*)d_in[15];
  const float* Wl0 = (const float*)d_in[16];
  const float* Wl1 = (const float*)d_in[17];
  const float* Wl2 = (const float*)d_in[18];
  const float* Wmix = (const float*)d_in[19];
  const float* bmix = (const float*)d_in[20];
  const float* Wz = (const float*)d_in[21];
  const float* bz = (const float*)d_in[22];
  const float* A_diag = (const float*)d_in[23];
  const float* A_U = (const float*)d_in[24];
  const float* A_V = (const float*)d_in[25];
  const float* Wamod = (const float*)d_in[26];
  const float* bamod = (const float*)d_in[27];
  const float* WB_w = (const float*)d_in[28];
  const float* bB = (const float*)d_in[29];
  const float* Wp1 = (const float*)d_in[30];
  const float* bp1 = (const float*)d_in[31];
  const float* lnp_s = (const float*)d_in[32];
  const float* lnp_b = (const float*)d_in[33];
  const float* Wp2 = (const float*)d_in[34];
  const float* bp2 = (const float*)d_in[35];
  const float* Wg = (const float*)d_in[36];
  const float* bg = (const float*)d_in[37];
  const float* U_p = (const float*)d_in[38];
  const float* U_w = (const float*)d_in[39];

  float* out_s = (float*)d_out;
  float* out_w = out_s + 2048 * 1024;
  float* out_p = out_w + 2048 * 512;

  char* base = (char*)d_ws;
  size_t off = 0;
  auto alloc = [&](size_t n) -> void* {
    void* p = base + off;
    off = (off + n + 255) & ~(size_t)255;
    return p;
  };

  // bf16 weights ([N,K]) ~71 MB
  __bf16* Wq1t   = (__bf16*)alloc((size_t)2048 * 2048 * 2);
  __bf16* Wq2t   = (__bf16*)alloc((size_t)256 * 2048 * 2);
  __bf16* Kb     = (__bf16*)alloc((size_t)3 * 4096 * 256 * 2);
  __bf16* Mt     = (__bf16*)alloc((size_t)3 * 1024 * 4096 * 2);
  __bf16* Wlt    = (__bf16*)alloc((size_t)3 * 1024 * 1024 * 2);
  __bf16* Wzt    = (__bf16*)alloc((size_t)1024 * 1024 * 2);
  __bf16* AVt    = (__bf16*)alloc((size_t)128 * 512 * 2);
  __bf16* AUb    = (__bf16*)alloc((size_t)512 * 128 * 2);
  __bf16* Wamodt = (__bf16*)alloc((size_t)512 * 1024 * 2);
  __bf16* WBt    = (__bf16*)alloc((size_t)512 * 2048 * 2);
  __bf16* Wp1t   = (__bf16*)alloc((size_t)2048 * 2048 * 2);
  __bf16* Wp2t   = (__bf16*)alloc((size_t)1024 * 2048 * 2);
  __bf16* Wgt    = (__bf16*)alloc((size_t)1024 * 3072 * 2);
  __bf16* Upb    = (__bf16*)alloc((size_t)1024 * 1024 * 2);
  __bf16* Uwb    = (__bf16*)alloc((size_t)1024 * 512 * 2);
  // split-K partial scratch: max 12 x 2048x1024 bf16 = 48 MB
  __bf16* P      = (__bf16*)alloc((size_t)12 * 2048 * 1024 * 2);
  // activations
  __bf16* cat_se  = (__bf16*)alloc((size_t)2048 * 2048 * 2);
  __bf16* hq      = (__bf16*)alloc((size_t)2048 * 2048 * 2);
  __bf16* qb      = (__bf16*)alloc((size_t)2048 * 256 * 2);
  __bf16* attn    = (__bf16*)alloc((size_t)3 * 2048 * 4096 * 2);
  __bf16* amb     = (__bf16*)alloc((size_t)3 * 2048 * 1024 * 2);
  __bf16* ctxcat  = (__bf16*)alloc((size_t)2048 * 3072 * 2);
  float*  mix     = (float*)alloc((size_t)2048 * 4 * 4);
  __bf16* cat_cz  = (__bf16*)alloc((size_t)2048 * 2048 * 2);
  __bf16* cat_pc  = (__bf16*)alloc((size_t)2048 * 2048 * 2);
  __bf16* cat_sec = (__bf16*)alloc((size_t)2048 * 3072 * 2);
  __bf16* wpb     = (__bf16*)alloc((size_t)2048 * 512 * 2);
  __bf16* uvtb    = (__bf16*)alloc((size_t)2048 * 128 * 2);
  __bf16* uv      = (__bf16*)alloc((size_t)2048 * 512 * 2);
  __bf16* amod    = (__bf16*)alloc((size_t)2048 * 512 * 2);
  __bf16* wBo     = (__bf16*)alloc((size_t)2048 * 512 * 2);
  __bf16* wtb     = (__bf16*)alloc((size_t)2048 * 512 * 2);
  // late buffers alias attn region (dead after the attn@M GEMM reads it)
  char* arec = (char*)attn;
  __bf16* ptb = (__bf16*)(arec);                             // 4 MB
  float*  pu  = (float*)(arec + (size_t)4  * 1024 * 1024);   // 8 MB
  float*  wu  = (float*)(arec + (size_t)12 * 1024 * 1024);   // 8 MB

  auto gemm = [&](auto tag, const __bf16* Ap, const __bf16* Bp, const float* bias,
                  void* C, int M, int N, int Ksub, int lda, int ldb, int ldc,
                  int bf16o, float sc, int batch, int nsplit, long sA, long sB, long sC) {
    constexpr int BM = decltype(tag)::value >> 16, BN = decltype(tag)::value & 0xffff;
    dim3 g(N / BN, M / BM, batch * nsplit);
    gemm_nt<BM, BN><<<g, 256, 0, stream>>>(Ap, Bp, bias, C, Ksub, lda, ldb, ldc,
                                           bf16o, sc, sA, sB, sC, nsplit);
  };
  auto reduce = [&](const __bf16* part, __bf16* out, const float* bias, int M, int N,
                    int ldo, long obs, long sC, int nsplit, float sc, int batch) {
    dim3 g((unsigned)((long)M * N / 2048), 1, batch);
    reduce_kernel<<<g, 256, 0, stream>>>(part, out, bias, N, ldo, obs, sC, nsplit, sc);
  };
  using T128 = std::integral_constant<int, (128 << 16) | 128>;
  using T12864 = std::integral_constant<int, (128 << 16) | 64>;
  using T64 = std::integral_constant<int, (64 << 16) | 64>;
  const long S21 = (long)2048 * 1024;   // 2048x1024 slice
  const long S22 = (long)2048 * 2048;
  const long S25 = (long)2048 * 512;
  const long S2q = (long)2048 * 256;

  // ---- batched weight transpose-conversions ----
  {
    TSegs t{};
    const float* s[15] = {Wq1, Wq2, M0, M1, M2, Wl0, Wl1, Wl2, Wz, A_V, Wamod,
                          WB_w, Wp1, Wp2, Wg};
    __bf16* d[15] = {Wq1t, Wq2t, Mt, Mt + (size_t)1024 * 4096, Mt + (size_t)2048 * 4096,
                     Wlt, Wlt + 1024 * 1024, Wlt + 2 * 1024 * 1024, Wzt, AVt, Wamodt,
                     WBt, Wp1t, Wp2t, Wgt};
    int R[15] = {2048, 2048, 4096, 4096, 4096, 1024, 1024, 1024, 1024, 512, 1024,
                 2048, 2048, 2048, 3072};
    int C[15] = {2048, 256, 1024, 1024, 1024, 1024, 1024, 1024, 1024, 128, 512,
                 512, 2048, 1024, 1024};
    int p = 0;
    for (int i = 0; i < 15; ++i) {
      t.src[i] = s[i]; t.dst[i] = d[i]; t.R[i] = R[i]; t.C[i] = C[i];
      t.prefix[i] = p; p += (R[i] >> 5) * (C[i] >> 5);
    }
    t.prefix[15] = p; t.nseg = 15;
    tconv_batch<<<p, 256, 0, stream>>>(t);
  }
  // ---- batched flat/strided fp32->bf16 ----
  {
    FSegs t{};
    const float* s[12] = {K0, K1, K2, A_U, U_p, U_w, s_prev, e_t, p_prev,
                          s_prev, e_t, w_prev};
    __bf16* d[12] = {Kb, Kb + 4096 * 256, Kb + 2 * 4096 * 256, AUb, Upb, Uwb,
                     cat_se, cat_se + 1024, cat_pc, cat_sec, cat_sec + 1024, wpb};
    int rows[12] = {1, 1, 1, 1, 1, 1, 2048, 2048, 2048, 2048, 2048, 1};
    int cols[12] = {4096 * 256, 4096 * 256, 4096 * 256, 512 * 128, 1024 * 1024,
                    1024 * 512, 1024, 1024, 1024, 1024, 1024, 2048 * 512};
    int sld[12] = {0, 0, 0, 0, 0, 0, 1024, 1024, 1024, 1024, 1024, 0};
    int dld[12] = {0, 0, 0, 0, 0, 0, 2048, 2048, 2048, 3072, 3072, 0};
    int p = 0;
    for (int i = 0; i < 12; ++i) {
      t.src[i] = s[i]; t.dst[i] = d[i]; t.rows[i] = rows[i]; t.cols[i] = cols[i];
      t.sld[i] = sld[i] ? sld[i] : cols[i]; t.dld[i] = dld[i] ? dld[i] : cols[i];
      t.prefix[i] = p;
      p += (int)(((long)rows[i] * cols[i] / 4 + 255) / 256);
    }
    t.prefix[12] = p; t.nseg = 12;
    f2b_batch<<<p, 256, 0, stream>>>(t);
  }

  // ---- q path ----
  gemm(T128{}, cat_se, Wq1t, nullptr, P, 2048, 2048, 512, 2048, 2048, 2048, 1, 1.f,
       1, 4, 0, 0, S22);
  reduce_ln_relu<<<2048, 256, 0, stream>>>(P, S22, 4, bq1, lnq_s, lnq_b, hq);
  gemm(T64{}, hq, Wq2t, nullptr, P, 2048, 256, 512, 2048, 2048, 256, 1, 1.f,
       1, 4, 0, 0, S2q);
  reduce(P, qb, bq2, 2048, 256, 256, 0, S2q, 4, 0.0625f, 1);

  // ---- CMS levels (batched z=3) ----
  gemm(T128{}, qb, Kb, nullptr, attn, 2048, 4096, 256, 256, 256, 4096, 1, 1.f,
       3, 1, 0, (long)4096 * 256, (long)2048 * 4096);
  softmax_bf16_kernel<<<3 * 2048, 256, 0, stream>>>(attn);
  gemm(T128{}, attn, Mt, nullptr, P, 2048, 1024, 1024, 4096, 4096, 1024, 1, 1.f,
       3, 4, (long)2048 * 4096, (long)1024 * 4096, S21);
  reduce(P, amb, nullptr, 2048, 1024, 1024, S21, S21, 4, 1.f, 3);
  // attn region dead from here (aliased by ptb/pu/wu)
  gemm(T128{}, amb, Wlt, nullptr, P, 2048, 1024, 256, 1024, 1024, 1024, 1, 1.f,
       3, 4, S21, (long)1024 * 1024, S21);
  reduce(P, ctxcat, nullptr, 2048, 1024, 3072, 1024, S21, 4, 1.f, 3);
  wmix_kernel<<<2048, 256, 0, stream>>>(ctxcat, Wmix, bmix, mix);
  ct_combine_kernel<<<8192, 256, 0, stream>>>(ctxcat, mix, cat_cz, cat_pc, cat_sec);

  // ---- wave path ----
  gemm(T12864{}, cat_se + 1024, Wzt, nullptr, P, 2048, 1024, 512, 2048, 1024,
       1024, 1, 1.f, 1, 2, 0, 0, S21);
  reduce(P, cat_cz + 1024, bz, 2048, 1024, 2048, 0, S21, 2, 1.f, 1);
  gemm(T64{}, wpb, AVt, nullptr, P, 2048, 128, 128, 512, 512, 128, 1, 1.f,
       1, 4, 0, 0, (long)2048 * 128);
  reduce(P, uvtb, nullptr, 2048, 128, 128, 0, (long)2048 * 128, 4, 1.f, 1);
  gemm(T64{}, uvtb, AUb, nullptr, uv, 2048, 512, 128, 128, 128, 512, 1, 1.f,
       1, 1, 0, 0, 0);
  gemm(T64{}, cat_cz, Wamodt, nullptr, P, 2048, 512, 512, 2048, 1024, 512, 1, 1.f,
       1, 2, 0, 0, S25);
  reduce(P, amod, bamod, 2048, 512, 512, 0, S25, 2, 1.f, 1);
  gemm(T64{}, cat_cz, WBt, nullptr, P + 2 * S25, 2048, 512, 1024, 2048, 2048, 512, 1, 1.f,
       1, 2, 0, 0, S25);
  reduce(P + 2 * S25, wBo, bB, 2048, 512, 512, 0, S25, 2, 1.f, 1);
  w_combine_kernel<<<4096, 256, 0, stream>>>(w_prev, uv, amod, wBo, A_diag, out_w, wtb);

  // ---- particle path ----
  gemm(T128{}, cat_pc, Wp1t, nullptr, P, 2048, 2048, 512, 2048, 2048, 2048, 1, 1.f,
       1, 4, 0, 0, S22);
  reduce_ln_relu<<<2048, 256, 0, stream>>>(P, S22, 4, bp1, lnp_s, lnp_b, hq);
  gemm(T128{}, hq, Wp2t, nullptr, P, 2048, 1024, 512, 2048, 2048, 1024, 1, 1.f,
       1, 4, 0, 0, S21);
  reduce_p_combine<<<1024, 256, 0, stream>>>(P, S21, 4, bp2, p_prev, out_p, ptb);

  // ---- gate + final ----
  gemm(T12864{}, cat_sec, Wgt, nullptr, P, 2048, 1024, 768, 3072, 3072, 1024, 1, 1.f,
       1, 4, 0, 0, S21);
  gemm(T12864{}, ptb, Upb, nullptr, pu, 2048, 1024, 1024, 1024, 1024, 1024, 0, 1.f,
       1, 1, 0, 0, 0);
  gemm(T12864{}, wtb, Uwb, nullptr, wu, 2048, 1024, 512, 512, 512, 1024, 0, 1.f,
       1, 1, 0, 0, 0);
  s_final_fused<<<1024, 256, 0, stream>>>(P, S21, 4, bg, s_prev, pu, wu, out_s);
}

// Round 5
// 681.738 us; speedup vs baseline: 1.1539x; 1.1539x over previous
//
#include <hip/hip_runtime.h>
#include <type_traits>

typedef __bf16 bf16x8 __attribute__((ext_vector_type(8)));
typedef __bf16 bf16x4 __attribute__((ext_vector_type(4)));
typedef float floatx4 __attribute__((ext_vector_type(4)));

__device__ __forceinline__ void gl_lds16(const __bf16* g, const __bf16* l) {
  __builtin_amdgcn_global_load_lds(
      (const __attribute__((address_space(1))) unsigned int*)g,
      (__attribute__((address_space(3))) unsigned int*)l, 16, 0, 0);
}

// =====================================================================
// Batched/split-K GEMM (m97 staging): C[M,N] = A[M,K] x Bt[N,K]^T
// blockIdx.z = zb*nsplit + zs; A/B advance zb*sA/sB + zs*K; C slice z*sC.
// =====================================================================
template <int BM, int BN>
__global__ __launch_bounds__(256)
void gemm_nt(const __bf16* __restrict__ A, const __bf16* __restrict__ Bt,
             const float* __restrict__ bias, void* __restrict__ Cv,
             int K, int lda, int ldb, int ldc, int bf16_out, float cscale,
             long sA, long sB, long sC, int nsplit)
{
  constexpr int MI = BM / 32;
  constexpr int NJ = BN / 32;
  __shared__ __align__(16) __bf16 As[BM * 32];
  __shared__ __align__(16) __bf16 Bs[BN * 32];
  const int tid = threadIdx.x;
  const int bm = blockIdx.y * BM, bn = blockIdx.x * BN;
  const int zb = blockIdx.z / nsplit, zs = blockIdx.z % nsplit;
  const __bf16* Ab = A  + (size_t)zb * sA + (size_t)zs * K;
  const __bf16* Bb = Bt + (size_t)zb * sB + (size_t)zs * K;
  const int wave = tid >> 6, lane = tid & 63;
  const int wm = (wave & 1) * (BM / 2), wn = (wave >> 1) * (BN / 2);
  const int lrow = lane & 15, quad = lane >> 4;
  const int srow = tid >> 2, scol = (tid & 3) << 3;

  const __bf16* Ap = Ab + (size_t)(bm + srow) * lda + scol;
  const __bf16* Bp = Bb + (size_t)(bn + srow) * ldb + scol;

  floatx4 acc[MI][NJ];
#pragma unroll
  for (int i = 0; i < MI; ++i)
#pragma unroll
    for (int j = 0; j < NJ; ++j) acc[i][j] = floatx4{0.f, 0.f, 0.f, 0.f};

  for (int k0 = 0; k0 < K; k0 += 32) {
#pragma unroll
    for (int r = 0; r < BM / 64; ++r)
      gl_lds16(Ap + (size_t)(64 * r) * lda + k0, &As[tid * 8 + r * 2048]);
#pragma unroll
    for (int r = 0; r < BN / 64; ++r)
      gl_lds16(Bp + (size_t)(64 * r) * ldb + k0, &Bs[tid * 8 + r * 2048]);
    __syncthreads();
    bf16x8 af[MI], bfr[NJ];
#pragma unroll
    for (int i = 0; i < MI; ++i)
      af[i] = *(const bf16x8*)&As[(wm + i * 16 + lrow) * 32 + (quad << 3)];
#pragma unroll
    for (int j = 0; j < NJ; ++j)
      bfr[j] = *(const bf16x8*)&Bs[(wn + j * 16 + lrow) * 32 + (quad << 3)];
#pragma unroll
    for (int i = 0; i < MI; ++i)
#pragma unroll
      for (int j = 0; j < NJ; ++j)
        acc[i][j] = __builtin_amdgcn_mfma_f32_16x16x32_bf16(af[i], bfr[j], acc[i][j], 0, 0, 0);
    __syncthreads();
  }

  if (bf16_out) {
    __bf16* C = (__bf16*)Cv + (size_t)blockIdx.z * sC;
#pragma unroll
    for (int i = 0; i < MI; ++i) {
      const int row0 = bm + wm + i * 16 + (quad << 2);
#pragma unroll
      for (int j = 0; j < NJ; ++j) {
        const int col = bn + wn + j * 16 + lrow;
        const float bv = bias ? bias[col] : 0.f;
#pragma unroll
        for (int r = 0; r < 4; ++r)
          C[(size_t)(row0 + r) * ldc + col] = (__bf16)((acc[i][j][r] + bv) * cscale);
      }
    }
  } else {
    float* C = (float*)Cv + (size_t)blockIdx.z * sC;
#pragma unroll
    for (int i = 0; i < MI; ++i) {
      const int row0 = bm + wm + i * 16 + (quad << 2);
#pragma unroll
      for (int j = 0; j < NJ; ++j) {
        const int col = bn + wn + j * 16 + lrow;
        const float bv = bias ? bias[col] : 0.f;
#pragma unroll
        for (int r = 0; r < 4; ++r)
          C[(size_t)(row0 + r) * ldc + col] = (acc[i][j][r] + bv) * cscale;
      }
    }
  }
}

// =====================================================================
// Grouped GEMM: independent GEMMs share one dispatch via descriptor table.
// 1D grid; block -> desc via blk0 prefix; same 128x128 m97 body.
// =====================================================================
struct GDesc {
  const __bf16* A; const __bf16* Bt; const float* bias; void* C;
  int K, lda, ldb, ldc, bf16o, ntiles, blk0; float scale;
};
struct GTable { GDesc d[8]; int nd; };

__global__ __launch_bounds__(256)
void gemm_group(GTable t)
{
  int s = 0;
  while (s + 1 < t.nd && (int)blockIdx.x >= t.d[s + 1].blk0) ++s;
  const GDesc d = t.d[s];
  const int local = blockIdx.x - d.blk0;
  const int bm = (local / d.ntiles) * 128, bn = (local % d.ntiles) * 128;

  __shared__ __align__(16) __bf16 As[128 * 32];
  __shared__ __align__(16) __bf16 Bs[128 * 32];
  const int tid = threadIdx.x;
  const int wave = tid >> 6, lane = tid & 63;
  const int wm = (wave & 1) << 6, wn = (wave >> 1) << 6;
  const int lrow = lane & 15, quad = lane >> 4;
  const int srow = tid >> 2, scol = (tid & 3) << 3;

  const __bf16* Ap = d.A + (size_t)(bm + srow) * d.lda + scol;
  const __bf16* Bp = d.Bt + (size_t)(bn + srow) * d.ldb + scol;

  floatx4 acc[4][4];
#pragma unroll
  for (int i = 0; i < 4; ++i)
#pragma unroll
    for (int j = 0; j < 4; ++j) acc[i][j] = floatx4{0.f, 0.f, 0.f, 0.f};

  for (int k0 = 0; k0 < d.K; k0 += 32) {
    gl_lds16(Ap + k0, &As[tid * 8]);
    gl_lds16(Ap + (size_t)64 * d.lda + k0, &As[tid * 8 + 2048]);
    gl_lds16(Bp + k0, &Bs[tid * 8]);
    gl_lds16(Bp + (size_t)64 * d.ldb + k0, &Bs[tid * 8 + 2048]);
    __syncthreads();
    bf16x8 af[4], bfr[4];
#pragma unroll
    for (int i = 0; i < 4; ++i) {
      af[i]  = *(const bf16x8*)&As[(wm + i * 16 + lrow) * 32 + (quad << 3)];
      bfr[i] = *(const bf16x8*)&Bs[(wn + i * 16 + lrow) * 32 + (quad << 3)];
    }
#pragma unroll
    for (int i = 0; i < 4; ++i)
#pragma unroll
      for (int j = 0; j < 4; ++j)
        acc[i][j] = __builtin_amdgcn_mfma_f32_16x16x32_bf16(af[i], bfr[j], acc[i][j], 0, 0, 0);
    __syncthreads();
  }

  if (d.bf16o) {
    __bf16* C = (__bf16*)d.C;
#pragma unroll
    for (int i = 0; i < 4; ++i) {
      const int row0 = bm + wm + i * 16 + (quad << 2);
#pragma unroll
      for (int j = 0; j < 4; ++j) {
        const int col = bn + wn + j * 16 + lrow;
        const float bv = d.bias ? d.bias[col] : 0.f;
#pragma unroll
        for (int r = 0; r < 4; ++r)
          C[(size_t)(row0 + r) * d.ldc + col] = (__bf16)((acc[i][j][r] + bv) * d.scale);
      }
    }
  } else {
    float* C = (float*)d.C;
#pragma unroll
    for (int i = 0; i < 4; ++i) {
      const int row0 = bm + wm + i * 16 + (quad << 2);
#pragma unroll
      for (int j = 0; j < 4; ++j) {
        const int col = bn + wn + j * 16 + lrow;
        const float bv = d.bias ? d.bias[col] : 0.f;
#pragma unroll
        for (int r = 0; r < 4; ++r)
          C[(size_t)(row0 + r) * d.ldc + col] = (acc[i][j][r] + bv) * d.scale;
      }
    }
  }
}

// ---- generic split-K reduce (x8) ----
__global__ __launch_bounds__(256)
void reduce_kernel(const __bf16* __restrict__ part, __bf16* __restrict__ out,
                   const float* __restrict__ bias, int N, int ldo, long obs,
                   long sC, int nsplit, float scale)
{
  const long idx = ((long)blockIdx.x * 256 + threadIdx.x) * 8;
  const int r = (int)(idx / N), c = (int)(idx % N);
  const __bf16* p0 = part + (size_t)blockIdx.z * nsplit * sC + idx;
  float a[8] = {0, 0, 0, 0, 0, 0, 0, 0};
  for (int s = 0; s < nsplit; ++s) {
    bf16x8 v = *(const bf16x8*)(p0 + (size_t)s * sC);
#pragma unroll
    for (int i = 0; i < 8; ++i) a[i] += (float)v[i];
  }
  if (bias) {
#pragma unroll
    for (int i = 0; i < 8; ++i) a[i] += bias[c + i];
  }
  bf16x8 o;
#pragma unroll
  for (int i = 0; i < 8; ++i) o[i] = (__bf16)(a[i] * scale);
  *(bf16x8*)(out + (size_t)blockIdx.z * obs + (size_t)r * ldo + c) = o;
}

// ---- fused: sum slices + bias -> LayerNorm -> ReLU -> bf16 (cols=2048) ----
__global__ __launch_bounds__(256)
void reduce_ln_relu(const __bf16* __restrict__ P, long sC, int nsplit,
                    const float* __restrict__ bias, const float* __restrict__ sc,
                    const float* __restrict__ bi, __bf16* __restrict__ out)
{
  const int row = blockIdx.x;
  const int c = threadIdx.x << 3;
  const __bf16* p0 = P + (size_t)row * 2048 + c;
  float f[8] = {0, 0, 0, 0, 0, 0, 0, 0};
  for (int s = 0; s < nsplit; ++s) {
    bf16x8 v = *(const bf16x8*)(p0 + (size_t)s * sC);
#pragma unroll
    for (int i = 0; i < 8; ++i) f[i] += (float)v[i];
  }
  float su = 0.f, ss = 0.f;
#pragma unroll
  for (int i = 0; i < 8; ++i) { f[i] += bias[c + i]; su += f[i]; ss += f[i] * f[i]; }
  __shared__ float shs[4], shss[4];
  const int lane = threadIdx.x & 63, w = threadIdx.x >> 6;
  for (int o = 32; o; o >>= 1) { su += __shfl_down(su, o, 64); ss += __shfl_down(ss, o, 64); }
  if (!lane) { shs[w] = su; shss[w] = ss; }
  __syncthreads();
  const float fs = shs[0] + shs[1] + shs[2] + shs[3];
  const float fss = shss[0] + shss[1] + shss[2] + shss[3];
  const float mu = fs * (1.f / 2048.f);
  const float rstd = rsqrtf(fss * (1.f / 2048.f) - mu * mu + 1e-6f);
  bf16x8 o;
#pragma unroll
  for (int i = 0; i < 8; ++i)
    o[i] = (__bf16)fmaxf((f[i] - mu) * rstd * sc[c + i] + bi[c + i], 0.f);
  *(bf16x8*)&out[(size_t)row * 2048 + c] = o;
}

// ---- fused: p_t = p_prev + (sum slices + bp2) ----
__global__ __launch_bounds__(256)
void reduce_p_combine(const __bf16* __restrict__ P, long sC, int nsplit,
                      const float* __restrict__ bp2, const float* __restrict__ p_prev,
                      float* __restrict__ p_out, __bf16* __restrict__ p_bf)
{
  const long idx = ((long)blockIdx.x * 256 + threadIdx.x) * 8;
  const int c = (int)(idx & 1023);
  float a[8] = {0, 0, 0, 0, 0, 0, 0, 0};
  for (int s = 0; s < nsplit; ++s) {
    bf16x8 v = *(const bf16x8*)(P + (size_t)s * sC + idx);
#pragma unroll
    for (int i = 0; i < 8; ++i) a[i] += (float)v[i];
  }
  bf16x8 ob;
#pragma unroll
  for (int i = 0; i < 8; ++i) {
    const float p = p_prev[idx + i] + a[i] + bp2[c + i];
    p_out[idx + i] = p;
    ob[i] = (__bf16)p;
  }
  *(bf16x8*)&p_bf[idx] = ob;
}

// ---- fused: g = sigmoid(sum slices + bg); s = clip(s_prev + g*pu + (1-g)*wu) ----
__global__ __launch_bounds__(256)
void s_final_fused(const __bf16* __restrict__ P, long sC, int nsplit,
                   const float* __restrict__ bg, const float* __restrict__ s_prev,
                   const float* __restrict__ pu, const float* __restrict__ wu,
                   float* __restrict__ s_out)
{
  const long idx = ((long)blockIdx.x * 256 + threadIdx.x) * 8;
  const int c = (int)(idx & 1023);
  float a[8] = {0, 0, 0, 0, 0, 0, 0, 0};
  for (int s = 0; s < nsplit; ++s) {
    bf16x8 v = *(const bf16x8*)(P + (size_t)s * sC + idx);
#pragma unroll
    for (int i = 0; i < 8; ++i) a[i] += (float)v[i];
  }
#pragma unroll
  for (int i = 0; i < 8; ++i) {
    const float g = 1.f / (1.f + expf(-(a[i] + bg[c + i])));
    float s = s_prev[idx + i] + g * pu[idx + i] + (1.f - g) * wu[idx + i];
    s_out[idx + i] = fminf(fmaxf(s, -10.f), 10.f);
  }
}

// ---- batched fp32 [R,C] -> bf16 [C,R] transpose-convert ----
struct TSegs {
  const float* src[16]; __bf16* dst[16];
  int R[16], C[16]; int prefix[17]; int nseg;
};
__global__ __launch_bounds__(256)
void tconv_batch(TSegs t)
{
  __shared__ float tile[32][33];
  int s = 0;
  while (s < t.nseg - 1 && (int)blockIdx.x >= t.prefix[s + 1]) ++s;
  const int local = blockIdx.x - t.prefix[s];
  const int Ct = t.C[s] >> 5;
  const int tr = local / Ct, tc = local - tr * Ct;
  const int r0 = tr << 5, c0 = tc << 5;
  const float* src = t.src[s];
  __bf16* dst = t.dst[s];
  const int R = t.R[s], C = t.C[s];
  const int x = threadIdx.x & 31, y = threadIdx.x >> 5;
#pragma unroll
  for (int i = 0; i < 32; i += 8)
    tile[y + i][x] = src[(size_t)(r0 + y + i) * C + c0 + x];
  __syncthreads();
#pragma unroll
  for (int i = 0; i < 32; i += 8)
    dst[(size_t)(c0 + y + i) * R + r0 + x] = (__bf16)tile[x][y + i];
}

// ---- batched fp32 -> bf16 (strided rows) ----
struct FSegs {
  const float* src[16]; __bf16* dst[16];
  int rows[16], cols[16], sld[16], dld[16]; int prefix[17]; int nseg;
};
__global__ __launch_bounds__(256)
void f2b_batch(FSegs t)
{
  int s = 0;
  while (s < t.nseg - 1 && (int)blockIdx.x >= t.prefix[s + 1]) ++s;
  const long e = ((long)(blockIdx.x - t.prefix[s]) * 256 + threadIdx.x) * 4;
  const int cols = t.cols[s];
  if (e >= (long)t.rows[s] * cols) return;
  const int r = (int)(e / cols), c = (int)(e % cols);
  float4 v = *(const float4*)(t.src[s] + (size_t)r * t.sld[s] + c);
  bf16x4 o;
  o[0] = (__bf16)v.x; o[1] = (__bf16)v.y; o[2] = (__bf16)v.z; o[3] = (__bf16)v.w;
  *(bf16x4*)(t.dst[s] + (size_t)r * t.dld[s] + c) = o;
}

// ---- in-place row softmax on bf16, cols=4096 ----
__global__ __launch_bounds__(256)
void softmax_bf16_kernel(__bf16* __restrict__ x)
{
  __bf16* xr = x + (size_t)blockIdx.x * 4096;
  bf16x8 v0 = *(const bf16x8*)&xr[threadIdx.x * 16];
  bf16x8 v1 = *(const bf16x8*)&xr[threadIdx.x * 16 + 8];
  float f[16];
#pragma unroll
  for (int i = 0; i < 8; ++i) { f[i] = (float)v0[i]; f[i + 8] = (float)v1[i]; }
  float m = f[0];
#pragma unroll
  for (int i = 1; i < 16; ++i) m = fmaxf(m, f[i]);
  __shared__ float sh[4];
  const int lane = threadIdx.x & 63, w = threadIdx.x >> 6;
  for (int o = 32; o; o >>= 1) m = fmaxf(m, __shfl_down(m, o, 64));
  if (!lane) sh[w] = m;
  __syncthreads();
  m = fmaxf(fmaxf(sh[0], sh[1]), fmaxf(sh[2], sh[3]));
  __syncthreads();
  float s = 0.f;
#pragma unroll
  for (int i = 0; i < 16; ++i) { f[i] = expf(f[i] - m); s += f[i]; }
  for (int o = 32; o; o >>= 1) s += __shfl_down(s, o, 64);
  if (!lane) sh[w] = s;
  __syncthreads();
  const float rs = 1.f / (sh[0] + sh[1] + sh[2] + sh[3]);
  bf16x8 o0, o1;
#pragma unroll
  for (int i = 0; i < 8; ++i) { o0[i] = (__bf16)(f[i] * rs); o1[i] = (__bf16)(f[i + 8] * rs); }
  *(bf16x8*)&xr[threadIdx.x * 16] = o0;
  *(bf16x8*)&xr[threadIdx.x * 16 + 8] = o1;
}

// ---- fused: ctx-reduce (Wl partials) + wmix softmax + c_t scatter ----
// P holds 3 levels x nsplit slices of [2048,1024]; one block per row.
__global__ __launch_bounds__(256)
void wmix_ct_fused(const __bf16* __restrict__ P, long sC, int nsplit,
                   const float* __restrict__ Wm, const float* __restrict__ bm,
                   __bf16* __restrict__ cz, __bf16* __restrict__ pc,
                   __bf16* __restrict__ sec)
{
  const int row = blockIdx.x;
  const int c = threadIdx.x << 2;  // 4 cols/thread
  float ctx[3][4];
  float a0 = 0.f, a1 = 0.f, a2 = 0.f;
#pragma unroll
  for (int l = 0; l < 3; ++l) {
    float v[4] = {0, 0, 0, 0};
    for (int s = 0; s < nsplit; ++s) {
      bf16x4 t4 = *(const bf16x4*)(P + (size_t)(l * nsplit + s) * sC +
                                   (size_t)row * 1024 + c);
#pragma unroll
      for (int i = 0; i < 4; ++i) v[i] += (float)t4[i];
    }
#pragma unroll
    for (int i = 0; i < 4; ++i) {
      ctx[l][i] = v[i];
      const int g = l * 1024 + c + i;
      a0 = fmaf(v[i], Wm[g * 3 + 0], a0);
      a1 = fmaf(v[i], Wm[g * 3 + 1], a1);
      a2 = fmaf(v[i], Wm[g * 3 + 2], a2);
    }
  }
  __shared__ float sh[3][4];
  __shared__ float mixs[3];
  const int lane = threadIdx.x & 63, w = threadIdx.x >> 6;
  for (int o = 32; o; o >>= 1) {
    a0 += __shfl_down(a0, o, 64); a1 += __shfl_down(a1, o, 64); a2 += __shfl_down(a2, o, 64);
  }
  if (!lane) { sh[0][w] = a0; sh[1][w] = a1; sh[2][w] = a2; }
  __syncthreads();
  if (threadIdx.x == 0) {
    float l0 = sh[0][0] + sh[0][1] + sh[0][2] + sh[0][3] + bm[0];
    float l1 = sh[1][0] + sh[1][1] + sh[1][2] + sh[1][3] + bm[1];
    float l2 = sh[2][0] + sh[2][1] + sh[2][2] + sh[2][3] + bm[2];
    float mm = fmaxf(l0, fmaxf(l1, l2));
    float e0 = expf(l0 - mm), e1 = expf(l1 - mm), e2 = expf(l2 - mm);
    float rs = 1.f / (e0 + e1 + e2);
    mixs[0] = e0 * rs; mixs[1] = e1 * rs; mixs[2] = e2 * rs;
  }
  __syncthreads();
  const float m0 = mixs[0], m1 = mixs[1], m2 = mixs[2];
  bf16x4 o;
#pragma unroll
  for (int i = 0; i < 4; ++i)
    o[i] = (__bf16)(m0 * ctx[0][i] + m1 * ctx[1][i] + m2 * ctx[2][i]);
  *(bf16x4*)&cz[(size_t)row * 2048 + c] = o;
  *(bf16x4*)&pc[(size_t)row * 2048 + 1024 + c] = o;
  *(bf16x4*)&sec[(size_t)row * 3072 + 2048 + c] = o;
}

// ---- w_t combine (bf16 uv/amod/wB) ----
__global__ __launch_bounds__(256)
void w_combine_kernel(const float* __restrict__ w_prev, const __bf16* __restrict__ uv,
                      const __bf16* __restrict__ amod, const __bf16* __restrict__ wB,
                      const float* __restrict__ A_diag, float* __restrict__ w_out,
                      __bf16* __restrict__ w_bf)
{
  const int idx = blockIdx.x * 256 + threadIdx.x;
  const int d = idx & 511;
  const float Ad = tanhf(A_diag[d]) * 0.9f;
  const float wl = fmaf(Ad, w_prev[idx], (float)uv[idx]);
  const float w = fmaf(tanhf((float)amod[idx]), wl, (float)wB[idx]);
  w_out[idx] = w;
  w_bf[idx] = (__bf16)w;
}

// =====================================================================
extern "C" void kernel_launch(void* const* d_in, const int* in_sizes, int n_in,
                              void* d_out, int out_size, void* d_ws, size_t ws_size,
                              hipStream_t stream)
{
  const float* s_prev = (const float*)d_in[0];
  const float* w_prev = (const float*)d_in[1];
  const float* p_prev = (const float*)d_in[2];
  const float* e_t    = (const float*)d_in[3];
  const float* M0 = (const float*)d_in[4];
  const float* M1 = (const float*)d_in[5];
  const float* M2 = (const float*)d_in[6];
  const float* K0 = (const float*)d_in[7];
  const float* K1 = (const float*)d_in[8];
  const float* K2 = (const float*)d_in[9];
  const float* Wq1 = (const float*)d_in[10];
  const float* bq1 = (const float*)d_in[11];
  const float* lnq_s = (const float*)d_in[12];
  const float* lnq_b = (const float*)d_in[13];
  const float* Wq2 = (const float*)d_in[14];
  const float* bq2 = (const float*)d_in[15];
  const float* Wl0 = (const float*)d_in[16];
  const float* Wl1 = (const float*)d_in[17];
  const float* Wl2 = (const float*)d_in[18];
  const float* Wmix = (const float*)d_in[19];
  const float* bmix = (const float*)d_in[20];
  const float* Wz = (const float*)d_in[21];
  const float* bz = (const float*)d_in[22];
  const float* A_diag = (const float*)d_in[23];
  const float* A_U = (const float*)d_in[24];
  const float* A_V = (const float*)d_in[25];
  const float* Wamod = (const float*)d_in[26];
  const float* bamod = (const float*)d_in[27];
  const float* WB_w = (const float*)d_in[28];
  const float* bB = (const float*)d_in[29];
  const float* Wp1 = (const float*)d_in[30];
  const float* bp1 = (const float*)d_in[31];
  const float* lnp_s = (const float*)d_in[32];
  const float* lnp_b = (const float*)d_in[33];
  const float* Wp2 = (const float*)d_in[34];
  const float* bp2 = (const float*)d_in[35];
  const float* Wg = (const float*)d_in[36];
  const float* bg = (const float*)d_in[37];
  const float* U_p = (const float*)d_in[38];
  const float* U_w = (const float*)d_in[39];

  float* out_s = (float*)d_out;
  float* out_w = out_s + 2048 * 1024;
  float* out_p = out_w + 2048 * 512;

  char* base = (char*)d_ws;
  size_t off = 0;
  auto alloc = [&](size_t n) -> void* {
    void* p = base + off;
    off = (off + n + 255) & ~(size_t)255;
    return p;
  };

  const long S21 = (long)2048 * 1024;
  const long S22 = (long)2048 * 2048;
  const long S2q = (long)2048 * 256;

  // bf16 weights ([N,K])
  __bf16* Wq1t   = (__bf16*)alloc((size_t)2048 * 2048 * 2);
  __bf16* Wq2t   = (__bf16*)alloc((size_t)256 * 2048 * 2);
  __bf16* Kb     = (__bf16*)alloc((size_t)3 * 4096 * 256 * 2);
  __bf16* Mt     = (__bf16*)alloc((size_t)3 * 1024 * 4096 * 2);
  __bf16* Wlt    = (__bf16*)alloc((size_t)3 * 1024 * 1024 * 2);
  __bf16* Wzt    = (__bf16*)alloc((size_t)1024 * 1024 * 2);
  __bf16* AUraw  = (__bf16*)alloc((size_t)512 * 128 * 2);
  __bf16* AVraw  = (__bf16*)alloc((size_t)512 * 128 * 2);
  __bf16* W2     = (__bf16*)alloc((size_t)512 * 512 * 2);
  __bf16* Wamodt = (__bf16*)alloc((size_t)512 * 1024 * 2);
  __bf16* WBt    = (__bf16*)alloc((size_t)512 * 2048 * 2);
  __bf16* Wp1t   = (__bf16*)alloc((size_t)2048 * 2048 * 2);
  __bf16* Wp2t   = (__bf16*)alloc((size_t)1024 * 2048 * 2);
  __bf16* Wgt    = (__bf16*)alloc((size_t)1024 * 3072 * 2);
  __bf16* Upb    = (__bf16*)alloc((size_t)1024 * 1024 * 2);
  __bf16* Uwb    = (__bf16*)alloc((size_t)1024 * 512 * 2);
  // partial scratch: 2*S22 (Wq1/Wp1) + 2*S21 (Wg) + 2*S21 (Wp2) = 12M elems
  __bf16* P   = (__bf16*)alloc((size_t)12 * 1024 * 1024 * 2);
  __bf16* Pg  = P + 2 * S22;            // Wg partials (alive till s_final)
  __bf16* Pp2 = P + 2 * S22 + 2 * S21;  // Wp2 partials
  // activations
  __bf16* cat_se  = (__bf16*)alloc((size_t)2048 * 2048 * 2);
  __bf16* hq      = (__bf16*)alloc((size_t)2048 * 2048 * 2);
  __bf16* qb      = (__bf16*)alloc((size_t)2048 * 256 * 2);
  __bf16* attn    = (__bf16*)alloc((size_t)3 * 2048 * 4096 * 2);
  __bf16* amb     = (__bf16*)alloc((size_t)3 * 2048 * 1024 * 2);
  __bf16* cat_cz  = (__bf16*)alloc((size_t)2048 * 2048 * 2);
  __bf16* cat_pc  = (__bf16*)alloc((size_t)2048 * 2048 * 2);
  __bf16* cat_sec = (__bf16*)alloc((size_t)2048 * 3072 * 2);
  __bf16* wpb     = (__bf16*)alloc((size_t)2048 * 512 * 2);
  __bf16* uv      = (__bf16*)alloc((size_t)2048 * 512 * 2);
  __bf16* amod    = (__bf16*)alloc((size_t)2048 * 512 * 2);
  __bf16* wBo     = (__bf16*)alloc((size_t)2048 * 512 * 2);
  __bf16* wtb     = (__bf16*)alloc((size_t)2048 * 512 * 2);
  // late buffers alias attn (dead after attn@M GEMM)
  char* arec = (char*)attn;
  __bf16* ptb = (__bf16*)(arec);                              // 4 MB
  float*  pu  = (float*)(arec + (size_t)4  * 1024 * 1024);    // 8 MB
  float*  wu  = (float*)(arec + (size_t)12 * 1024 * 1024);    // 8 MB

  auto gemm = [&](const __bf16* Ap, const __bf16* Bp, const float* bias,
                  void* C, int M, int N, int Ksub, int lda, int ldb, int ldc,
                  int bf16o, float sc, int batch, int nsplit, long sA, long sB, long sC) {
    dim3 g(N / 128, M / 128, batch * nsplit);
    gemm_nt<128, 128><<<g, 256, 0, stream>>>(Ap, Bp, bias, C, Ksub, lda, ldb, ldc,
                                             bf16o, sc, sA, sB, sC, nsplit);
  };
  auto reduce = [&](const __bf16* part, __bf16* out, const float* bias, int M, int N,
                    int ldo, long obs, long sC, int nsplit, float sc, int batch) {
    dim3 g((unsigned)((long)M * N / 2048), 1, batch);
    reduce_kernel<<<g, 256, 0, stream>>>(part, out, bias, N, ldo, obs, sC, nsplit, sc);
  };
  auto group = [&](GTable& t) {
    int total = t.d[t.nd - 1].blk0 +
                ((t.nd >= 1) ? 0 : 0);  // computed by caller below
    (void)total;
  };

  // ---- conversions ----
  {
    TSegs t{};
    const float* s[14] = {Wq1, Wq2, M0, M1, M2, Wl0, Wl1, Wl2, Wz, Wamod,
                          WB_w, Wp1, Wp2, Wg};
    __bf16* d[14] = {Wq1t, Wq2t, Mt, Mt + (size_t)1024 * 4096, Mt + (size_t)2048 * 4096,
                     Wlt, Wlt + 1024 * 1024, Wlt + 2 * 1024 * 1024, Wzt, Wamodt,
                     WBt, Wp1t, Wp2t, Wgt};
    int R[14] = {2048, 2048, 4096, 4096, 4096, 1024, 1024, 1024, 1024, 1024,
                 2048, 2048, 2048, 3072};
    int C[14] = {2048, 256, 1024, 1024, 1024, 1024, 1024, 1024, 1024, 512,
                 512, 2048, 1024, 1024};
    int p = 0;
    for (int i = 0; i < 14; ++i) {
      t.src[i] = s[i]; t.dst[i] = d[i]; t.R[i] = R[i]; t.C[i] = C[i];
      t.prefix[i] = p; p += (R[i] >> 5) * (C[i] >> 5);
    }
    t.prefix[14] = p; t.nseg = 14;
    tconv_batch<<<p, 256, 0, stream>>>(t);
  }
  {
    FSegs t{};
    const float* s[13] = {K0, K1, K2, A_U, A_V, U_p, U_w, s_prev, e_t, p_prev,
                          s_prev, e_t, w_prev};
    __bf16* d[13] = {Kb, Kb + 4096 * 256, Kb + 2 * 4096 * 256, AUraw, AVraw, Upb, Uwb,
                     cat_se, cat_se + 1024, cat_pc, cat_sec, cat_sec + 1024, wpb};
    int rows[13] = {1, 1, 1, 1, 1, 1, 1, 2048, 2048, 2048, 2048, 2048, 1};
    int cols[13] = {4096 * 256, 4096 * 256, 4096 * 256, 512 * 128, 512 * 128,
                    1024 * 1024, 1024 * 512, 1024, 1024, 1024, 1024, 1024, 2048 * 512};
    int sld[13] = {0, 0, 0, 0, 0, 0, 0, 1024, 1024, 1024, 1024, 1024, 0};
    int dld[13] = {0, 0, 0, 0, 0, 0, 0, 2048, 2048, 2048, 3072, 3072, 0};
    int p = 0;
    for (int i = 0; i < 13; ++i) {
      t.src[i] = s[i]; t.dst[i] = d[i]; t.rows[i] = rows[i]; t.cols[i] = cols[i];
      t.sld[i] = sld[i] ? sld[i] : cols[i]; t.dld[i] = dld[i] ? dld[i] : cols[i];
      t.prefix[i] = p;
      p += (int)(((long)rows[i] * cols[i] / 4 + 255) / 256);
    }
    t.prefix[13] = p; t.nseg = 13;
    f2b_batch<<<p, 256, 0, stream>>>(t);
  }

  // ---- G1: {Wq1 s0, Wq1 s1, Wz (z_t), W2 = A_U @ A_V^T} ----
  {
    GTable t{};
    t.d[0] = {cat_se,        Wq1t,        nullptr, P,           1024, 2048, 2048, 2048, 1, 16, 0,   1.f};
    t.d[1] = {cat_se + 1024, Wq1t + 1024, nullptr, P + S22,     1024, 2048, 2048, 2048, 1, 16, 256, 1.f};
    t.d[2] = {cat_se + 1024, Wzt,         bz,      cat_cz + 1024, 1024, 2048, 1024, 2048, 1, 8, 512, 1.f};
    t.d[3] = {AUraw,         AVraw,       nullptr, W2,          128,  128,  128,  512,  1, 4, 640, 1.f};
    t.nd = 4;
    gemm_group<<<656, 256, 0, stream>>>(t);
  }
  reduce_ln_relu<<<2048, 256, 0, stream>>>(P, S22, 2, bq1, lnq_s, lnq_b, hq);

  // ---- G2: {Wq2 s0, Wq2 s1, uv = wpb @ W2^T} ----
  {
    GTable t{};
    t.d[0] = {hq,        Wq2t,        nullptr, P,       1024, 2048, 2048, 256, 1, 2, 0,  1.f};
    t.d[1] = {hq + 1024, Wq2t + 1024, nullptr, P + S2q, 1024, 2048, 2048, 256, 1, 2, 32, 1.f};
    t.d[2] = {wpb,       W2,          nullptr, uv,      512,  512,  512,  512, 1, 4, 64, 1.f};
    t.nd = 3;
    gemm_group<<<128, 256, 0, stream>>>(t);
  }
  reduce(P, qb, bq2, 2048, 256, 256, 0, S2q, 2, 0.0625f, 1);

  // ---- scores (batch 3) ----
  gemm(qb, Kb, nullptr, attn, 2048, 4096, 256, 256, 256, 4096, 1, 1.f,
       3, 1, 0, (long)4096 * 256, (long)2048 * 4096);
  softmax_bf16_kernel<<<3 * 2048, 256, 0, stream>>>(attn);
  // ---- attn@M (batch 3, nsplit 2 = 768 blocks) ----
  gemm(attn, Mt, nullptr, P, 2048, 1024, 2048, 4096, 4096, 1024, 1, 1.f,
       3, 2, (long)2048 * 4096, (long)1024 * 4096, S21);
  reduce(P, amb, nullptr, 2048, 1024, 1024, S21, S21, 2, 1.f, 3);
  // attn region dead from here (aliased by ptb/pu/wu)
  // ---- ctx@Wl (batch 3, nsplit 2) -> partials consumed by wmix_ct ----
  gemm(amb, Wlt, nullptr, P, 2048, 1024, 512, 1024, 1024, 1024, 1, 1.f,
       3, 2, S21, (long)1024 * 1024, S21);
  wmix_ct_fused<<<2048, 256, 0, stream>>>(P, S21, 2, Wmix, bmix,
                                          cat_cz, cat_pc, cat_sec);

  // ---- G6: {amod, WB, Wp1 s0, Wp1 s1, Wg s0, Wg s1} = 896 blocks ----
  {
    GTable t{};
    t.d[0] = {cat_cz,         Wamodt,      bamod,   amod,      1024, 2048, 1024, 512,  1, 4,  0,   1.f};
    t.d[1] = {cat_cz,         WBt,         bB,      wBo,       2048, 2048, 2048, 512,  1, 4,  64,  1.f};
    t.d[2] = {cat_pc,         Wp1t,        nullptr, P,         1024, 2048, 2048, 2048, 1, 16, 128, 1.f};
    t.d[3] = {cat_pc + 1024,  Wp1t + 1024, nullptr, P + S22,   1024, 2048, 2048, 2048, 1, 16, 384, 1.f};
    t.d[4] = {cat_sec,        Wgt,         nullptr, Pg,        1536, 3072, 3072, 1024, 1, 8,  640, 1.f};
    t.d[5] = {cat_sec + 1536, Wgt + 1536,  nullptr, Pg + S21,  1536, 3072, 3072, 1024, 1, 8,  768, 1.f};
    t.nd = 6;
    gemm_group<<<896, 256, 0, stream>>>(t);
  }
  reduce_ln_relu<<<2048, 256, 0, stream>>>(P, S22, 2, bp1, lnp_s, lnp_b, hq);
  w_combine_kernel<<<4096, 256, 0, stream>>>(w_prev, uv, amod, wBo, A_diag, out_w, wtb);

  // ---- G7: {Wp2 s0, Wp2 s1, Uw} = 384 blocks ----
  {
    GTable t{};
    t.d[0] = {hq,        Wp2t,        nullptr, Pp2,       1024, 2048, 2048, 1024, 1, 8, 0,   1.f};
    t.d[1] = {hq + 1024, Wp2t + 1024, nullptr, Pp2 + S21, 1024, 2048, 2048, 1024, 1, 8, 128, 1.f};
    t.d[2] = {wtb,       Uwb,         nullptr, wu,        512,  512,  512,  1024, 0, 8, 256, 1.f};
    t.nd = 3;
    gemm_group<<<384, 256, 0, stream>>>(t);
  }
  reduce_p_combine<<<1024, 256, 0, stream>>>(Pp2, S21, 2, bp2, p_prev, out_p, ptb);

  // ---- Up -> pu ----
  gemm(ptb, Upb, nullptr, pu, 2048, 1024, 1024, 1024, 1024, 1024, 0, 1.f,
       1, 1, 0, 0, 0);
  s_final_fused<<<1024, 256, 0, stream>>>(Pg, S21, 2, bg, s_prev, pu, wu, out_s);
}